// Round 14
// baseline (104.327 us; speedup 1.0000x reference)
//
#include <hip/hip_runtime.h>
#include <stdint.h>

#define NQ 10
#define DIMQ 1024
#define BATCH 4096

typedef float f32x2 __attribute__((ext_vector_type(2)));

#if __has_builtin(__builtin_amdgcn_permlane16_swap)
#define HAS_PL16 1
#else
#define HAS_PL16 0
#endif

// Layer's 10 CNOTs composed as a GF(2)-linear index map (scatter form).
__host__ __device__ constexpr int cperm_c(int x, int r) {
  for (int q = 0; q < NQ; ++q) {
    const int c = 9 - q;
    int t = c - r; if (t < 0) t += NQ;
    x ^= ((x >> c) & 1) << t;
  }
  return x;
}
// Epilogue sign masks (layer-3 perm r=4 folded into signs); layout
// idx = (h<<9)|(e<<6)|lane: lane mask 6 bits, e mask 3 bits, h mask 1 bit.
constexpr int amask(int q) {
  int a = 0;
  for (int b = 0; b < 6; ++b) a |= ((cperm_c(1 << b, 4) >> (9 - q)) & 1) << b;
  return a;
}
constexpr int mmask(int q) {
  int m = 0;
  for (int b = 0; b < 3; ++b) m |= ((cperm_c(1 << (6 + b), 4) >> (9 - q)) & 1) << b;
  return m;
}
constexpr int hmask(int q) { return (cperm_c(512, 4) >> (9 - q)) & 1; }

// ------------------------------------------------------- gate precompute ---
// R13-proven parallel prep (~3 us): one thread per table idx.
__global__ __launch_bounds__(256) void prep_g(const float* __restrict__ wts,
                                              float* __restrict__ Gg) {
  const int idx = blockIdx.x * 256 + threadIdx.x;   // grid 4 x 256 = 1024
  if (idx < 40) {
    float th = wts[idx * 3 + 1];
    ((float2*)Gg)[idx] = make_float2(cosf(0.5f * th), sinf(0.5f * th));
  }
  f32x2* D0 = (f32x2*)(Gg + 128);
  f32x2* E  = D0 + 1024;           // E0, E1, E2 consecutive (1024 each)
  auto sphase = [&](int l, int i, int comp) {   // comp: 0=phi, 2=omega
    float s = 0.f;
    #pragma unroll
    for (int q = 0; q < 10; ++q) {              // wts loads are uniform
      float sg = ((i >> (9 - q)) & 1) ? 0.5f : -0.5f;
      s += sg * wts[(l * 10 + q) * 3 + comp];
    }
    return s;
  };
  float p0 = sphase(0, idx, 0);
  D0[idx] = (f32x2){cosf(p0), sinf(p0)};
  #pragma unroll
  for (int l = 0; l < 3; ++l) {
    float a = sphase(l, idx, 2) + sphase(l + 1, cperm_c(idx, l + 1), 0);
    E[l * 1024 + idx] = (f32x2){cosf(a), sinf(a)};
  }
}

// ---- VALU-pipe lane shuffles ----
template<int CTRL>
__device__ __forceinline__ float dpp1(float x) {
  return __int_as_float(
      __builtin_amdgcn_update_dpp(0, __float_as_int(x), CTRL, 0xF, 0xF, true));
}
// quad_perm xor1=0xB1, xor2=0x4E, xor3=0x1B; row_half_mirror(^7)=0x141;
// row_ror:8 = 0x128 == xor8 within a 16-lane row.
template<int P>   // P = lane bit, 0..3 (DPP only)
__device__ __forceinline__ float shufl(float x) {
  if constexpr (P == 0)      return dpp1<0xB1>(x);
  else if constexpr (P == 1) return dpp1<0x4E>(x);
  else if constexpr (P == 2) return dpp1<0x141>(dpp1<0x1B>(x));
  else                       return dpp1<0x128>(x);   // row_ror:8 == ^8
}
__device__ __forceinline__ float x16(float x, bool hi) {
#if HAS_PL16
  auto rr = __builtin_amdgcn_permlane16_swap(__float_as_uint(x),
                                             __float_as_uint(x), false, false);
  return __uint_as_float(hi ? rr[0] : rr[1]);
#else
  (void)hi;
  return __int_as_float(__builtin_amdgcn_ds_swizzle(__float_as_int(x), 0x401F));
#endif
}

// Wave sum -> uniform scalar.
__device__ __forceinline__ float red64(float v) {
  v += dpp1<0xB1>(v);
  v += dpp1<0x4E>(v);
  v += dpp1<0x141>(dpp1<0x1B>(v));   // ^4
  v += dpp1<0x128>(v);               // ^8 (row_ror:8)
#if HAS_PL16
  { auto rr = __builtin_amdgcn_permlane16_swap(__float_as_uint(v),
                                               __float_as_uint(v), false, false);
    v = __uint_as_float(rr[0]) + __uint_as_float(rr[1]); }
#else
  v += __int_as_float(__builtin_amdgcn_ds_swizzle(__float_as_int(v), 0x401F));
#endif
  auto p = __builtin_amdgcn_permlane32_swap(__float_as_uint(v),
                                            __float_as_uint(v), false, false);
  return __uint_as_float(p[0]) + __uint_as_float(p[1]);
}

// ---- REAL Givens rotations on 8 amps/lane ----
template<int MT>   // e bits 2..0 (idx bits 8:6)
__device__ __forceinline__ void ry_reg(f32x2 (&s)[8], float2 cs) {
  const float c = cs.x, sn = cs.y;
  #pragma unroll
  for (int e0 = 0; e0 < 8; ++e0) {
    if (e0 & MT) continue;
    const int e1 = e0 | MT;
    f32x2 x0 = s[e0], x1 = s[e1];
    s[e0] = c * x0 - sn * x1;
    s[e1] = sn * x0 + c * x1;
  }
}
template<int P>    // lane bits 3..0 via DPP
__device__ __forceinline__ void ry_dpp(f32x2 (&s)[8], float2 cs, int lane) {
  const float c = cs.x;
  const float ss = ((lane >> P) & 1) ? cs.y : -cs.y;
  #pragma unroll
  for (int e = 0; e < 8; ++e) {
    f32x2 o;
    o.x = shufl<P>(s[e].x);
    o.y = shufl<P>(s[e].y);
    s[e] = c * s[e] + ss * o;
  }
}
__device__ __forceinline__ void ry16(f32x2 (&s)[8], float2 cs, int lane) {
  const bool H = (lane & 16) != 0;
  const float c = cs.x;
  const float ss = H ? cs.y : -cs.y;
  #pragma unroll
  for (int e = 0; e < 8; ++e) {
    f32x2 o;
    o.x = x16(s[e].x, H);
    o.y = x16(s[e].y, H);
    s[e] = c * s[e] + ss * o;
  }
}
__device__ __forceinline__ void ry5(f32x2 (&s)[8], float2 cs, int lane) {
  const int L = lane >> 5;
  const float c = cs.x;
  const float ss = L ? cs.y : -cs.y;
  #pragma unroll
  for (int e = 0; e < 8; ++e) {
    unsigned xr = __float_as_uint(s[e].x), xi = __float_as_uint(s[e].y);
    auto rr = __builtin_amdgcn_permlane32_swap(xr, xr, false, false);
    auto ri = __builtin_amdgcn_permlane32_swap(xi, xi, false, false);
    f32x2 o;
    o.x = __uint_as_float(L ? rr[0] : rr[1]);
    o.y = __uint_as_float(L ? ri[0] : ri[1]);
    s[e] = c * s[e] + ss * o;
  }
}

// RY on bit 9 (wave bit): streaming LDS exchange (R4 lesson: consume the
// partner value immediately; R5-proven skeleton). FIRST also exchanges the
// norm partial. h=0: new = c*x - sn*o ; h=1: new = c*x + sn*o.
template<bool FIRST>
__device__ __forceinline__ void ry_wave(f32x2 (&s)[8], float2 cs,
                                        f32x2* __restrict__ buf,
                                        int lane, int h, float& ss) {
  f32x2* wp = buf + ((h << 9) | lane);
  #pragma unroll
  for (int e = 0; e < 8; ++e) wp[e << 6] = s[e];
  if (FIRST && lane == 0) buf[1024 + h] = (f32x2){ss, 0.f};
  __syncthreads();
  const float c = cs.x;
  const float sn = h ? cs.y : -cs.y;
  const f32x2* rp = buf + (((h ^ 1) << 9) | lane);
  #pragma unroll
  for (int e = 0; e < 8; ++e) {
    f32x2 o = rp[e << 6];
    s[e] = c * s[e] + sn * o;
  }
  if (FIRST) ss += buf[1024 + (h ^ 1)].x;
  __syncthreads();
}

// CNOT permutation: bijective block-level scatter (both waves concurrent,
// no collision), barrier, gather, barrier.
template<int R>
__device__ __forceinline__ void perm_state(f32x2 (&s)[8], f32x2* __restrict__ buf,
                                           int lane, int h) {
  constexpr int K0=cperm_c(1,R),  K1=cperm_c(2,R),  K2=cperm_c(4,R),
                K3=cperm_c(8,R),  K4=cperm_c(16,R), K5=cperm_c(32,R),
                C6=cperm_c(64,R), C7=cperm_c(128,R),
                C8=cperm_c(256,R),C9=cperm_c(512,R);
  const int yl = ((lane & 1)  ? K0 : 0) ^ ((lane & 2)  ? K1 : 0) ^
                 ((lane & 4)  ? K2 : 0) ^ ((lane & 8)  ? K3 : 0) ^
                 ((lane & 16) ? K4 : 0) ^ ((lane & 32) ? K5 : 0) ^
                 (h ? C9 : 0);
  #pragma unroll
  for (int e = 0; e < 8; ++e) {
    const int y = yl ^ (((e & 1) ? C6 : 0) ^ ((e & 2) ? C7 : 0) ^
                        ((e & 4) ? C8 : 0));
    buf[y] = s[e];
  }
  __syncthreads();
  const f32x2* rp = buf + ((h << 9) | lane);
  #pragma unroll
  for (int e = 0; e < 8; ++e) s[e] = rp[e << 6];
  __syncthreads();
}

template<int LYR>
__device__ __forceinline__ void do_layer(f32x2 (&s)[8],
                                         const float2* __restrict__ ryc,
                                         const f32x2* __restrict__ Etab,
                                         f32x2* __restrict__ buf,
                                         int lane, int h, float& ss) {
  // E-prefetch first: the ~10-gate VALU sequence below hides the L2 latency.
  f32x2 et[8];
  if constexpr (LYR < 3) {
    const f32x2* El = Etab + LYR * 1024 + (h << 9);
    #pragma unroll
    for (int e = 0; e < 8; ++e) et[e] = El[(e << 6) | lane];
  }
  const float2* G = ryc + LYR * 10;
  ry_wave<LYR == 0>(s, G[0], buf, lane, h, ss);   // q0 -> bit9 (wave bit)
  ry_reg<4>(s, G[1]);          // q1 -> bit8 = e bit2
  ry_reg<2>(s, G[2]);          // q2 -> bit7 = e bit1
  ry_reg<1>(s, G[3]);          // q3 -> bit6 = e bit0
  ry5     (s, G[4], lane);     // q4 -> bit5 (permlane32_swap)
  ry16    (s, G[5], lane);     // q5 -> bit4 (permlane16_swap / swizzle)
  ry_dpp<3>(s, G[6], lane);    // q6 -> bit3 (row_ror:8)
  ry_dpp<2>(s, G[7], lane);    // q7 -> bit2 (DPP)
  ry_dpp<1>(s, G[8], lane);    // q8 -> bit1 (DPP)
  ry_dpp<0>(s, G[9], lane);    // q9 -> bit0 (DPP)
  if constexpr (LYR < 3) {
    #pragma unroll
    for (int e = 0; e < 8; ++e) {        // merged omega(l)+phi(l+1) diagonal
      f32x2 t = et[e];
      f32x2 r;
      r.x = s[e].x * t.x - s[e].y * t.y;
      r.y = s[e].x * t.y + s[e].y * t.x;
      s[e] = r;
    }
    perm_state<LYR + 1>(s, buf, lane, h);
  }
  // layer 3: omega-diag dropped (pure phase); perm folded into epilogue signs
}

// In-register Walsh-Hadamard stage over the 3 e-bits.
template<int M>
__device__ __forceinline__ void wht(float (&hh)[8]) {
  #pragma unroll
  for (int e0 = 0; e0 < 8; ++e0) {
    if (e0 & M) continue;
    float u = hh[e0], v = hh[e0 | M];
    hh[e0] = u + v;
    hh[e0 | M] = u - v;
  }
}
template<int Q>
__device__ __forceinline__ float zfin(const float (&hh)[8], int lane, int h) {
  constexpr int aq = amask(Q);
  constexpr int mq = mmask(Q);
  constexpr int hq = hmask(Q);
  float t = hh[mq];
  int par = (__builtin_popcount(lane & aq) + (hq ? h : 0)) & 1;
  t = par ? -t : t;
  return red64(t);
}

// ------------------------------------------------------- fused simulation ---
// R14: half-row per wave (idx = h<<9 | e<<6 | lane), 8192 waves = 8/SIMD
// (R13 post-mortem: ~3K inst/wave but wall 4x the issue floor at 4 waves/SIMD
// -> latency-bound; double TLP). R5-proven skeleton, R11/R12 math. 8.3 KB
// LDS/block -> 16 blocks/CU; launch_bounds(128,4) = 64-VGPR budget (R5: 52).
__global__ __launch_bounds__(128, 4) void vqc_sim(const float* __restrict__ X,
                                                  const float* __restrict__ Gg,
                                                  const float* __restrict__ W,
                                                  const float* __restrict__ bias,
                                                  float* __restrict__ out) {
  __shared__ f32x2 buf[1026];        // 1024 state slots + 2 norm slots
  __shared__ float zbuf[2][10];
  const int lane = threadIdx.x & 63;
  const int h = threadIdx.x >> 6;    // wave bit = index bit 9
  const int row = blockIdx.x;
  const float2* ryc = (const float2*)Gg;
  const f32x2* D0   = (const f32x2*)(Gg + 128);
  const f32x2* Etab = D0 + 1024;

  f32x2 s[8];

  // ---- load own half; init = x * D_phi^0; per-wave norm partial ----
  const float* xr = X + (size_t)row * DIMQ + (h << 9);
  const f32x2* D0h = D0 + (h << 9);
  float ss = 0.f;
  #pragma unroll
  for (int e = 0; e < 8; ++e) {
    float v = xr[(e << 6) | lane];
    ss += v * v;
    s[e] = v * D0h[(e << 6) | lane];
  }
  ss = red64(ss);

  do_layer<0>(s, ryc, Etab, buf, lane, h, ss);   // first exchange sums ss
  do_layer<1>(s, ryc, Etab, buf, lane, h, ss);
  do_layer<2>(s, ryc, Etab, buf, lane, h, ss);
  do_layer<3>(s, ryc, Etab, buf, lane, h, ss);

  const float rn2 = 1.0f / ss;       // uniform probability scale

  // ---- probs -> z via WHT (layer-3 perm r=4 folded into signs) ----
  float hh[8];
  #pragma unroll
  for (int e = 0; e < 8; ++e) hh[e] = s[e].x * s[e].x + s[e].y * s[e].y;
  wht<1>(hh); wht<2>(hh); wht<4>(hh);

  float z[10];
  z[0] = zfin<0>(hh, lane, h);
  z[1] = zfin<1>(hh, lane, h);
  z[2] = zfin<2>(hh, lane, h);
  z[3] = zfin<3>(hh, lane, h);
  z[4] = zfin<4>(hh, lane, h);
  z[5] = zfin<5>(hh, lane, h);
  z[6] = zfin<6>(hh, lane, h);
  z[7] = zfin<7>(hh, lane, h);
  z[8] = zfin<8>(hh, lane, h);
  z[9] = zfin<9>(hh, lane, h);

  // ---- cross-wave combine + linear head ----
  if (lane < 10) zbuf[h][lane] = z[lane];
  __syncthreads();
  if (h == 0 && lane < 16) {
    float acc = bias[lane];
    #pragma unroll
    for (int q = 0; q < 10; ++q)
      acc += (zbuf[0][q] + zbuf[1][q]) * rn2 * W[lane * 10 + q];
    out[(size_t)row * 16 + lane] = acc;
  }
}

extern "C" void kernel_launch(void* const* d_in, const int* in_sizes, int n_in,
                              void* d_out, int out_size, void* d_ws, size_t ws_size,
                              hipStream_t stream) {
  const float* X    = (const float*)d_in[0];
  const float* wts  = (const float*)d_in[1];
  const float* W    = (const float*)d_in[2];
  const float* bias = (const float*)d_in[3];
  float* out = (float*)d_out;
  float* Gg = (float*)d_ws;   // 80 ry floats + pad + D0/E tables = 33 KB

  hipLaunchKernelGGL(prep_g,  dim3(4),     dim3(256), 0, stream, wts, Gg);
  hipLaunchKernelGGL(vqc_sim, dim3(BATCH), dim3(128), 0, stream, X, Gg, W, bias, out);
}

// Round 15
// 97.513 us; speedup vs baseline: 1.0699x; 1.0699x over previous
//
#include <hip/hip_runtime.h>
#include <stdint.h>

#define NQ 10
#define DIMQ 1024
#define BATCH 4096

typedef float f32x2 __attribute__((ext_vector_type(2)));

#if __has_builtin(__builtin_amdgcn_permlane16_swap)
#define HAS_PL16 1
#else
#define HAS_PL16 0
#endif

// Layer's 10 CNOTs composed as a GF(2)-linear index map (scatter form).
__host__ __device__ constexpr int cperm_c(int x, int r) {
  for (int q = 0; q < NQ; ++q) {
    const int c = 9 - q;
    int t = c - r; if (t < 0) t += NQ;
    x ^= ((x >> c) & 1) << t;
  }
  return x;
}
// Epilogue sign masks (layer-3 perm r=4 folded into signs).
constexpr int amask(int q) {
  int a = 0;
  for (int b = 0; b < 6; ++b) a |= ((cperm_c(1 << b, 4) >> (9 - q)) & 1) << b;
  return a;
}
constexpr int mmask(int q) {
  int m = 0;
  for (int b = 0; b < 4; ++b) m |= ((cperm_c(1 << (6 + b), 4) >> (9 - q)) & 1) << b;
  return m;
}

// ------------------------------------------------------- gate precompute ---
// R13-proven parallel prep: one thread per table idx. R15: E stored
// PRE-PACKED as float4 {c, c, -s, s} so the merged-diagonal complex multiply
// is 2 packed ops (R9's coefficient-pair trick applied to the tables).
__global__ __launch_bounds__(256) void prep_g(const float* __restrict__ wts,
                                              float* __restrict__ Gg) {
  const int idx = blockIdx.x * 256 + threadIdx.x;   // grid 4 x 256 = 1024
  if (idx < 40) {
    float th = wts[idx * 3 + 1];
    ((float2*)Gg)[idx] = make_float2(cosf(0.5f * th), sinf(0.5f * th));
  }
  f32x2* D0 = (f32x2*)(Gg + 128);
  float4* E = (float4*)(D0 + 1024);     // E0, E1, E2 consecutive (1024 each)
  auto sphase = [&](int l, int i, int comp) {   // comp: 0=phi, 2=omega
    float s = 0.f;
    #pragma unroll
    for (int q = 0; q < 10; ++q) {              // wts loads are uniform
      float sg = ((i >> (9 - q)) & 1) ? 0.5f : -0.5f;
      s += sg * wts[(l * 10 + q) * 3 + comp];
    }
    return s;
  };
  float p0 = sphase(0, idx, 0);
  D0[idx] = (f32x2){cosf(p0), sinf(p0)};
  #pragma unroll
  for (int l = 0; l < 3; ++l) {
    float a = sphase(l, idx, 2) + sphase(l + 1, cperm_c(idx, l + 1), 0);
    E[l * 1024 + idx] = make_float4(cosf(a), cosf(a), -sinf(a), sinf(a));
  }
}

// ---- VALU-pipe lane shuffles ----
template<int CTRL>
__device__ __forceinline__ float dpp1(float x) {
  return __int_as_float(
      __builtin_amdgcn_update_dpp(0, __float_as_int(x), CTRL, 0xF, 0xF, true));
}
// quad_perm xor1=0xB1, xor2=0x4E, xor3=0x1B; row_half_mirror(^7)=0x141;
// row_ror:8 = 0x128 == xor8 within a 16-lane row.
template<int P>   // P = lane bit, 0..3 (DPP only)
__device__ __forceinline__ float shufl(float x) {
  if constexpr (P == 0)      return dpp1<0xB1>(x);
  else if constexpr (P == 1) return dpp1<0x4E>(x);
  else if constexpr (P == 2) return dpp1<0x141>(dpp1<0x1B>(x));
  else                       return dpp1<0x128>(x);   // row_ror:8 == ^8
}

__device__ __forceinline__ f32x2 swapv(f32x2 v) {
  return __builtin_shufflevector(v, v, 1, 0);
}

// Wave sum -> uniform scalar.
__device__ __forceinline__ float red64(float v) {
  v += dpp1<0xB1>(v);
  v += dpp1<0x4E>(v);
  v += dpp1<0x141>(dpp1<0x1B>(v));   // ^4
  v += dpp1<0x128>(v);               // ^8 (row_ror:8)
#if HAS_PL16
  { auto rr = __builtin_amdgcn_permlane16_swap(__float_as_uint(v),
                                               __float_as_uint(v), false, false);
    v = __uint_as_float(rr[0]) + __uint_as_float(rr[1]); }
#else
  v += __int_as_float(__builtin_amdgcn_ds_swizzle(__float_as_int(v), 0x401F));
#endif
  auto p = __builtin_amdgcn_permlane32_swap(__float_as_uint(v),
                                            __float_as_uint(v), false, false);
  return __uint_as_float(p[0]) + __uint_as_float(p[1]);
}

// ---- REAL Givens rotations on 16 amps/lane ----
template<int MT>   // e bits 3..0 (idx bits 9:6)
__device__ __forceinline__ void ry_reg(f32x2 (&s)[16], float2 cs) {
  const float c = cs.x, sn = cs.y;
  #pragma unroll
  for (int e0 = 0; e0 < 16; ++e0) {
    if (e0 & MT) continue;
    const int e1 = e0 | MT;
    f32x2 x0 = s[e0], x1 = s[e1];
    s[e0] = c * x0 - sn * x1;
    s[e1] = sn * x0 + c * x1;
  }
}
template<int P>    // lane bits 3..0 via DPP
__device__ __forceinline__ void ry_dpp(f32x2 (&s)[16], float2 cs, int lane) {
  const float c = cs.x;
  const float ss = ((lane >> P) & 1) ? cs.y : -cs.y;
  #pragma unroll
  for (int e = 0; e < 16; ++e) {
    f32x2 o;
    o.x = shufl<P>(s[e].x);
    o.y = shufl<P>(s[e].y);
    s[e] = c * s[e] + ss * o;
  }
}
// lane bit 4 (xor16): select-free when permlane16_swap exists — both
// half-broadcasts returned; coefficients (one = 0) hoisted per gate.
__device__ __forceinline__ void ry16(f32x2 (&s)[16], float2 cs, int lane) {
  const bool H = (lane & 16) != 0;
#if HAS_PL16
  const float b0 = H ? cs.y : 0.f;     // coeff on rr[0] = x[lane & ~16]
  const float b1 = H ? 0.f : -cs.y;    // coeff on rr[1] = x[lane |  16]
  const float c = cs.x;
  #pragma unroll
  for (int e = 0; e < 16; ++e) {
    auto rr = __builtin_amdgcn_permlane16_swap(__float_as_uint(s[e].x),
                                               __float_as_uint(s[e].x), false, false);
    auto ri = __builtin_amdgcn_permlane16_swap(__float_as_uint(s[e].y),
                                               __float_as_uint(s[e].y), false, false);
    f32x2 o0, o1;
    o0.x = __uint_as_float(rr[0]); o0.y = __uint_as_float(ri[0]);
    o1.x = __uint_as_float(rr[1]); o1.y = __uint_as_float(ri[1]);
    s[e] = c * s[e] + b0 * o0 + b1 * o1;
  }
#else
  const float c = cs.x;
  const float ss = H ? cs.y : -cs.y;
  #pragma unroll
  for (int e = 0; e < 16; ++e) {
    f32x2 o;
    o.x = __int_as_float(__builtin_amdgcn_ds_swizzle(__float_as_int(s[e].x), 0x401F));
    o.y = __int_as_float(__builtin_amdgcn_ds_swizzle(__float_as_int(s[e].y), 0x401F));
    s[e] = c * s[e] + ss * o;
  }
#endif
}
// lane bit 5 (xor32): select-free permlane32_swap (rr[0]=lo-broadcast,
// rr[1]=hi-broadcast; R7-verified).
__device__ __forceinline__ void ry5(f32x2 (&s)[16], float2 cs, int lane) {
  const int L = lane >> 5;
  const float c = cs.x;
  const float a0 = L ? cs.y : 0.f;     // coeff on rr[0] (lo half value)
  const float a1 = L ? 0.f : -cs.y;    // coeff on rr[1] (hi half value)
  #pragma unroll
  for (int e = 0; e < 16; ++e) {
    auto rr = __builtin_amdgcn_permlane32_swap(__float_as_uint(s[e].x),
                                               __float_as_uint(s[e].x), false, false);
    auto ri = __builtin_amdgcn_permlane32_swap(__float_as_uint(s[e].y),
                                               __float_as_uint(s[e].y), false, false);
    f32x2 o0, o1;
    o0.x = __uint_as_float(rr[0]); o0.y = __uint_as_float(ri[0]);
    o1.x = __uint_as_float(rr[1]); o1.y = __uint_as_float(ri[1]);
    s[e] = c * s[e] + a0 * o0 + a1 * o1;
  }
}

// CNOT permutation via private per-wave LDS slice (same-wave DS in-order,
// no barrier).
template<int R>
__device__ __forceinline__ void perm_state(f32x2 (&s)[16], f32x2* __restrict__ L,
                                           int lane) {
  constexpr int K0=cperm_c(1,R),  K1=cperm_c(2,R),  K2=cperm_c(4,R),
                K3=cperm_c(8,R),  K4=cperm_c(16,R), K5=cperm_c(32,R),
                C6=cperm_c(64,R), C7=cperm_c(128,R),
                C8=cperm_c(256,R),C9=cperm_c(512,R);
  const int yl = ((lane & 1)  ? K0 : 0) ^ ((lane & 2)  ? K1 : 0) ^
                 ((lane & 4)  ? K2 : 0) ^ ((lane & 8)  ? K3 : 0) ^
                 ((lane & 16) ? K4 : 0) ^ ((lane & 32) ? K5 : 0);
  #pragma unroll
  for (int e = 0; e < 16; ++e) {
    const int ye = ((e & 1) ? C6 : 0) ^ ((e & 2) ? C7 : 0) ^
                   ((e & 4) ? C8 : 0) ^ ((e & 8) ? C9 : 0);
    L[yl ^ ye] = s[e];
  }
  #pragma unroll
  for (int e = 0; e < 16; ++e) s[e] = L[(e << 6) | lane];
}

template<int LYR>
__device__ __forceinline__ void do_layer(f32x2 (&s)[16],
                                         const float2* __restrict__ ryc,
                                         const float4* __restrict__ Etab,
                                         f32x2* __restrict__ L, int lane) {
  // E-prefetch first: the 10-gate VALU sequence below hides the L2 latency.
  float4 et[16];
  if constexpr (LYR < 3) {
    const float4* El = Etab + LYR * 1024;
    #pragma unroll
    for (int e = 0; e < 16; ++e) et[e] = El[(e << 6) | lane];
  }
  const float2* G = ryc + LYR * 10;
  ry_reg<8>(s, G[0]);          // q0 -> bit9
  ry_reg<4>(s, G[1]);          // q1 -> bit8
  ry_reg<2>(s, G[2]);          // q2 -> bit7
  ry_reg<1>(s, G[3]);          // q3 -> bit6
  ry5     (s, G[4], lane);     // q4 -> bit5 (permlane32_swap, select-free)
  ry16    (s, G[5], lane);     // q5 -> bit4 (permlane16_swap, select-free)
  ry_dpp<3>(s, G[6], lane);    // q6 -> bit3 (row_ror:8)
  ry_dpp<2>(s, G[7], lane);    // q7 -> bit2 (DPP)
  ry_dpp<1>(s, G[8], lane);    // q8 -> bit1 (DPP)
  ry_dpp<0>(s, G[9], lane);    // q9 -> bit0 (DPP)
  if constexpr (LYR < 3) {
    #pragma unroll
    for (int e = 0; e < 16; ++e) {       // merged diag: 2 packed ops
      f32x2 e1; e1.x = et[e].x; e1.y = et[e].y;   // (c, c)
      f32x2 e2; e2.x = et[e].z; e2.y = et[e].w;   // (-s, s)
      s[e] = e1 * s[e] + e2 * swapv(s[e]);
    }
    perm_state<LYR + 1>(s, L, lane);
  }
  // layer 3: omega-diag dropped (pure phase); perm folded into epilogue signs
}

// In-register Walsh-Hadamard stage over the 4 e-bits.
template<int M>
__device__ __forceinline__ void wht(float (&h)[16]) {
  #pragma unroll
  for (int e0 = 0; e0 < 16; ++e0) {
    if (e0 & M) continue;
    float u = h[e0], v = h[e0 | M];
    h[e0] = u + v;
    h[e0 | M] = u - v;
  }
}
template<int Q>
__device__ __forceinline__ float zfin(const float (&h)[16], int lane) {
  constexpr int aq = amask(Q);
  constexpr int mq = mmask(Q);
  float t = h[mq];
  if constexpr (aq != 0) {
    int par = __builtin_popcount(lane & aq) & 1;
    t = par ? -t : t;
  }
  return red64(t);
}

// ------------------------------------------------------- fused simulation ---
// R13 structure (proven best): one row per wave, 16 amps/lane, unrolled
// layers, 4 waves/SIMD, zero __syncthreads, E-prefetch. R15: packed E-pairs,
// select-free ry5/ry16, rn2 folded into the output dot.
__global__ __launch_bounds__(256, 2) void vqc_sim(const float* __restrict__ X,
                                                  const float* __restrict__ Gg,
                                                  const float* __restrict__ W,
                                                  const float* __restrict__ bias,
                                                  float* __restrict__ out) {
  __shared__ f32x2 lds[4][DIMQ];     // 32 KB perm slices (per-wave private)
  const int lane = threadIdx.x & 63;
  const int w = threadIdx.x >> 6;
  const int row = blockIdx.x * 4 + w;
  f32x2* L = lds[w];
  const float2* ryc = (const float2*)Gg;
  const f32x2* D0   = (const f32x2*)(Gg + 128);
  const float4* Etab = (const float4*)(D0 + 1024);

  f32x2 s[16];

  // ---- load; init state = x * D_phi^0 (first diagonal on real input) ----
  const float* xr = X + (size_t)row * DIMQ;
  float ss = 0.f;
  #pragma unroll
  for (int e = 0; e < 16; ++e) {
    float v = xr[(e << 6) | lane];
    ss += v * v;
    s[e] = v * D0[(e << 6) | lane];
  }
  const float rn2 = 1.0f / red64(ss);   // uniform probability scale

  do_layer<0>(s, ryc, Etab, L, lane);
  do_layer<1>(s, ryc, Etab, L, lane);
  do_layer<2>(s, ryc, Etab, L, lane);
  do_layer<3>(s, ryc, Etab, L, lane);

  // ---- probs -> z via WHT (layer-3 perm r=4 folded into signs) ----
  float h[16];
  #pragma unroll
  for (int e = 0; e < 16; ++e) h[e] = s[e].x * s[e].x + s[e].y * s[e].y;
  wht<1>(h); wht<2>(h); wht<4>(h); wht<8>(h);

  float z[10];
  z[0] = zfin<0>(h, lane);
  z[1] = zfin<1>(h, lane);
  z[2] = zfin<2>(h, lane);
  z[3] = zfin<3>(h, lane);
  z[4] = zfin<4>(h, lane);
  z[5] = zfin<5>(h, lane);
  z[6] = zfin<6>(h, lane);
  z[7] = zfin<7>(h, lane);
  z[8] = zfin<8>(h, lane);
  z[9] = zfin<9>(h, lane);

  // ---- linear head (rn2 applied once) ----
  if (lane < 16) {
    float acc = 0.f;
    #pragma unroll
    for (int q = 0; q < 10; ++q) acc += z[q] * W[lane * 10 + q];
    out[(size_t)row * 16 + lane] = bias[lane] + rn2 * acc;
  }
}

extern "C" void kernel_launch(void* const* d_in, const int* in_sizes, int n_in,
                              void* d_out, int out_size, void* d_ws, size_t ws_size,
                              hipStream_t stream) {
  const float* X    = (const float*)d_in[0];
  const float* wts  = (const float*)d_in[1];
  const float* W    = (const float*)d_in[2];
  const float* bias = (const float*)d_in[3];
  float* out = (float*)d_out;
  float* Gg = (float*)d_ws;   // ryc 128 + D0 2048 + E 12288 floats ~= 58 KB

  hipLaunchKernelGGL(prep_g,  dim3(4),         dim3(256), 0, stream, wts, Gg);
  hipLaunchKernelGGL(vqc_sim, dim3(BATCH / 4), dim3(256), 0, stream, X, Gg, W, bias, out);
}

// Round 16
// 94.634 us; speedup vs baseline: 1.1024x; 1.0304x over previous
//
#include <hip/hip_runtime.h>
#include <stdint.h>

#define NQ 10
#define DIMQ 1024
#define BATCH 4096

typedef float f32x2 __attribute__((ext_vector_type(2)));

#if __has_builtin(__builtin_amdgcn_permlane16_swap)
#define HAS_PL16 1
#else
#define HAS_PL16 0
#endif

// Layer's 10 CNOTs composed as a GF(2)-linear index map (scatter form).
__host__ __device__ constexpr int cperm_c(int x, int r) {
  for (int q = 0; q < NQ; ++q) {
    const int c = 9 - q;
    int t = c - r; if (t < 0) t += NQ;
    x ^= ((x >> c) & 1) << t;
  }
  return x;
}
// Epilogue sign masks (layer-3 perm r=4 folded into signs).
constexpr int amask(int q) {
  int a = 0;
  for (int b = 0; b < 6; ++b) a |= ((cperm_c(1 << b, 4) >> (9 - q)) & 1) << b;
  return a;
}
constexpr int mmask(int q) {
  int m = 0;
  for (int b = 0; b < 4; ++b) m |= ((cperm_c(1 << (6 + b), 4) >> (9 - q)) & 1) << b;
  return m;
}

// ------------------------------------------------------- gate precompute ---
// Per gate: float4 (c, s, t, 0) with theta = th/2, c=cos, s=sin,
// t=tan(theta/2) for the 3-shear (lifting) form of the reg-bit gates.
// E tables pre-packed float4 {c, c, -s, s} (R15-proven).
__global__ __launch_bounds__(256) void prep_g(const float* __restrict__ wts,
                                              float* __restrict__ Gg) {
  const int idx = blockIdx.x * 256 + threadIdx.x;   // grid 4 x 256 = 1024
  if (idx < 40) {
    float th = wts[idx * 3 + 1];
    ((float4*)Gg)[idx] = make_float4(cosf(0.5f * th), sinf(0.5f * th),
                                     tanf(0.25f * th), 0.f);
  }
  f32x2* D0 = (f32x2*)(Gg + 256);
  float4* E = (float4*)(D0 + 1024);     // E0, E1, E2 consecutive (1024 each)
  auto sphase = [&](int l, int i, int comp) {   // comp: 0=phi, 2=omega
    float s = 0.f;
    #pragma unroll
    for (int q = 0; q < 10; ++q) {              // wts loads are uniform
      float sg = ((i >> (9 - q)) & 1) ? 0.5f : -0.5f;
      s += sg * wts[(l * 10 + q) * 3 + comp];
    }
    return s;
  };
  float p0 = sphase(0, idx, 0);
  D0[idx] = (f32x2){cosf(p0), sinf(p0)};
  #pragma unroll
  for (int l = 0; l < 3; ++l) {
    float a = sphase(l, idx, 2) + sphase(l + 1, cperm_c(idx, l + 1), 0);
    E[l * 1024 + idx] = make_float4(cosf(a), cosf(a), -sinf(a), sinf(a));
  }
}

// ---- VALU-pipe lane shuffles ----
template<int CTRL>
__device__ __forceinline__ float dpp1(float x) {
  return __int_as_float(
      __builtin_amdgcn_update_dpp(0, __float_as_int(x), CTRL, 0xF, 0xF, true));
}
// quad_perm xor1=0xB1, xor2=0x4E, xor3=0x1B; row_half_mirror(^7)=0x141;
// row_ror:8 = 0x128 == xor8 within a 16-lane row.
template<int P>   // P = lane bit: 0,1 (quad_perm) or 3 (row_ror:8)
__device__ __forceinline__ float shufl(float x) {
  if constexpr (P == 0)      return dpp1<0xB1>(x);
  else if constexpr (P == 1) return dpp1<0x4E>(x);
  else                       return dpp1<0x128>(x);   // row_ror:8 == ^8
}

__device__ __forceinline__ f32x2 swapv(f32x2 v) {
  return __builtin_shufflevector(v, v, 1, 0);
}

// Wave sum -> uniform scalar.
__device__ __forceinline__ float red64(float v) {
  v += dpp1<0xB1>(v);
  v += dpp1<0x4E>(v);
  v += dpp1<0x141>(dpp1<0x1B>(v));   // ^4
  v += dpp1<0x128>(v);               // ^8 (row_ror:8)
#if HAS_PL16
  { auto rr = __builtin_amdgcn_permlane16_swap(__float_as_uint(v),
                                               __float_as_uint(v), false, false);
    v = __uint_as_float(rr[0]) + __uint_as_float(rr[1]); }
#else
  v += __int_as_float(__builtin_amdgcn_ds_swizzle(__float_as_int(v), 0x401F));
#endif
  auto p = __builtin_amdgcn_permlane32_swap(__float_as_uint(v),
                                            __float_as_uint(v), false, false);
  return __uint_as_float(p[0]) + __uint_as_float(p[1]);
}

// ---- REAL Givens rotations on 16 amps/lane ----
// Reg-bit gate in 3-shear (lifting) form: 3 pk FMA/pair instead of 4 pk ops.
// R = [[1,-t],[0,1]]*[[1,0],[s,1]]*[[1,-t],[0,1]], t = tan(theta/2).
template<int MT>   // e bits 3..0 (idx bits 9:6)
__device__ __forceinline__ void ry_reg(f32x2 (&s)[16], float t, float sn) {
  #pragma unroll
  for (int e0 = 0; e0 < 16; ++e0) {
    if (e0 & MT) continue;
    const int e1 = e0 | MT;
    s[e0] = s[e0] - t * s[e1];
    s[e1] = s[e1] + sn * s[e0];
    s[e0] = s[e0] - t * s[e1];
  }
}
template<int P>    // lane bits 0,1,3 via single DPP
__device__ __forceinline__ void ry_dpp(f32x2 (&s)[16], float2 cs, int lane) {
  const float c = cs.x;
  const float ss = ((lane >> P) & 1) ? cs.y : -cs.y;
  #pragma unroll
  for (int e = 0; e < 16; ++e) {
    f32x2 o;
    o.x = shufl<P>(s[e].x);
    o.y = shufl<P>(s[e].y);
    s[e] = c * s[e] + ss * o;
  }
}
// lane bit 2 (xor4): double-DPP (6 VALU/amp) offloaded to the near-idle DS
// pipe via ds_swizzle (2 DS + 2 VALU/amp). R16: pipe balancing — R7's
// DS-saturation premise no longer holds (~170 DS ops/row vs 930 then).
__device__ __forceinline__ void ry_ds4(f32x2 (&s)[16], float2 cs, int lane) {
  const float c = cs.x;
  const float ss = ((lane >> 2) & 1) ? cs.y : -cs.y;
  #pragma unroll
  for (int e = 0; e < 16; ++e) {
    f32x2 o;
    o.x = __int_as_float(__builtin_amdgcn_ds_swizzle(__float_as_int(s[e].x), 0x101F));
    o.y = __int_as_float(__builtin_amdgcn_ds_swizzle(__float_as_int(s[e].y), 0x101F));
    s[e] = c * s[e] + ss * o;
  }
}
// lane bit 4 (xor16): select-free permlane16_swap (R15-proven).
__device__ __forceinline__ void ry16(f32x2 (&s)[16], float2 cs, int lane) {
  const bool H = (lane & 16) != 0;
#if HAS_PL16
  const float b0 = H ? cs.y : 0.f;     // coeff on rr[0] = x[lane & ~16]
  const float b1 = H ? 0.f : -cs.y;    // coeff on rr[1] = x[lane |  16]
  const float c = cs.x;
  #pragma unroll
  for (int e = 0; e < 16; ++e) {
    auto rr = __builtin_amdgcn_permlane16_swap(__float_as_uint(s[e].x),
                                               __float_as_uint(s[e].x), false, false);
    auto ri = __builtin_amdgcn_permlane16_swap(__float_as_uint(s[e].y),
                                               __float_as_uint(s[e].y), false, false);
    f32x2 o0, o1;
    o0.x = __uint_as_float(rr[0]); o0.y = __uint_as_float(ri[0]);
    o1.x = __uint_as_float(rr[1]); o1.y = __uint_as_float(ri[1]);
    s[e] = c * s[e] + b0 * o0 + b1 * o1;
  }
#else
  const float c = cs.x;
  const float ss = H ? cs.y : -cs.y;
  #pragma unroll
  for (int e = 0; e < 16; ++e) {
    f32x2 o;
    o.x = __int_as_float(__builtin_amdgcn_ds_swizzle(__float_as_int(s[e].x), 0x401F));
    o.y = __int_as_float(__builtin_amdgcn_ds_swizzle(__float_as_int(s[e].y), 0x401F));
    s[e] = c * s[e] + ss * o;
  }
#endif
}
// lane bit 5 (xor32): select-free permlane32_swap (R15-proven).
__device__ __forceinline__ void ry5(f32x2 (&s)[16], float2 cs, int lane) {
  const int L = lane >> 5;
  const float c = cs.x;
  const float a0 = L ? cs.y : 0.f;     // coeff on rr[0] (lo half value)
  const float a1 = L ? 0.f : -cs.y;    // coeff on rr[1] (hi half value)
  #pragma unroll
  for (int e = 0; e < 16; ++e) {
    auto rr = __builtin_amdgcn_permlane32_swap(__float_as_uint(s[e].x),
                                               __float_as_uint(s[e].x), false, false);
    auto ri = __builtin_amdgcn_permlane32_swap(__float_as_uint(s[e].y),
                                               __float_as_uint(s[e].y), false, false);
    f32x2 o0, o1;
    o0.x = __uint_as_float(rr[0]); o0.y = __uint_as_float(ri[0]);
    o1.x = __uint_as_float(rr[1]); o1.y = __uint_as_float(ri[1]);
    s[e] = c * s[e] + a0 * o0 + a1 * o1;
  }
}

// CNOT permutation via private per-wave LDS slice (same-wave DS in-order,
// no barrier).
template<int R>
__device__ __forceinline__ void perm_state(f32x2 (&s)[16], f32x2* __restrict__ L,
                                           int lane) {
  constexpr int K0=cperm_c(1,R),  K1=cperm_c(2,R),  K2=cperm_c(4,R),
                K3=cperm_c(8,R),  K4=cperm_c(16,R), K5=cperm_c(32,R),
                C6=cperm_c(64,R), C7=cperm_c(128,R),
                C8=cperm_c(256,R),C9=cperm_c(512,R);
  const int yl = ((lane & 1)  ? K0 : 0) ^ ((lane & 2)  ? K1 : 0) ^
                 ((lane & 4)  ? K2 : 0) ^ ((lane & 8)  ? K3 : 0) ^
                 ((lane & 16) ? K4 : 0) ^ ((lane & 32) ? K5 : 0);
  #pragma unroll
  for (int e = 0; e < 16; ++e) {
    const int ye = ((e & 1) ? C6 : 0) ^ ((e & 2) ? C7 : 0) ^
                   ((e & 4) ? C8 : 0) ^ ((e & 8) ? C9 : 0);
    L[yl ^ ye] = s[e];
  }
  #pragma unroll
  for (int e = 0; e < 16; ++e) s[e] = L[(e << 6) | lane];
}

template<int LYR>
__device__ __forceinline__ void do_layer(f32x2 (&s)[16],
                                         const float4* __restrict__ gq,
                                         const float4* __restrict__ Etab,
                                         f32x2* __restrict__ L, int lane) {
  // E-prefetch first: the 10-gate VALU sequence below hides the L2 latency.
  float4 et[16];
  if constexpr (LYR < 3) {
    const float4* El = Etab + LYR * 1024;
    #pragma unroll
    for (int e = 0; e < 16; ++e) et[e] = El[(e << 6) | lane];
  }
  const float4* G = gq + LYR * 10;
  ry_reg<8>(s, G[0].z, G[0].y);          // q0 -> bit9 (3-shear)
  ry_reg<4>(s, G[1].z, G[1].y);          // q1 -> bit8
  ry_reg<2>(s, G[2].z, G[2].y);          // q2 -> bit7
  ry_reg<1>(s, G[3].z, G[3].y);          // q3 -> bit6
  ry5     (s, make_float2(G[4].x, G[4].y), lane);  // q4 -> bit5 (permlane32)
  ry16    (s, make_float2(G[5].x, G[5].y), lane);  // q5 -> bit4 (permlane16)
  ry_dpp<3>(s, make_float2(G[6].x, G[6].y), lane); // q6 -> bit3 (row_ror:8)
  ry_ds4  (s, make_float2(G[7].x, G[7].y), lane);  // q7 -> bit2 (ds_swizzle)
  ry_dpp<1>(s, make_float2(G[8].x, G[8].y), lane); // q8 -> bit1 (DPP)
  ry_dpp<0>(s, make_float2(G[9].x, G[9].y), lane); // q9 -> bit0 (DPP)
  if constexpr (LYR < 3) {
    #pragma unroll
    for (int e = 0; e < 16; ++e) {       // merged diag: 2 packed ops
      f32x2 e1; e1.x = et[e].x; e1.y = et[e].y;   // (c, c)
      f32x2 e2; e2.x = et[e].z; e2.y = et[e].w;   // (-s, s)
      s[e] = e1 * s[e] + e2 * swapv(s[e]);
    }
    perm_state<LYR + 1>(s, L, lane);
  }
  // layer 3: omega-diag dropped (pure phase); perm folded into epilogue signs
}

// In-register Walsh-Hadamard stage over the 4 e-bits.
template<int M>
__device__ __forceinline__ void wht(float (&h)[16]) {
  #pragma unroll
  for (int e0 = 0; e0 < 16; ++e0) {
    if (e0 & M) continue;
    float u = h[e0], v = h[e0 | M];
    h[e0] = u + v;
    h[e0 | M] = u - v;
  }
}
template<int Q>
__device__ __forceinline__ float zfin(const float (&h)[16], int lane) {
  constexpr int aq = amask(Q);
  constexpr int mq = mmask(Q);
  float t = h[mq];
  if constexpr (aq != 0) {
    int par = __builtin_popcount(lane & aq) & 1;
    t = par ? -t : t;
  }
  return red64(t);
}

// ------------------------------------------------------- fused simulation ---
// R13/R15 structure (proven best): one row per wave, 16 amps/lane, unrolled
// layers, 4 waves/SIMD, zero __syncthreads, E-prefetch, packed E-pairs,
// select-free permlane gates. R16: 3-shear reg gates + ds_swizzle ^4.
__global__ __launch_bounds__(256, 2) void vqc_sim(const float* __restrict__ X,
                                                  const float* __restrict__ Gg,
                                                  const float* __restrict__ W,
                                                  const float* __restrict__ bias,
                                                  float* __restrict__ out) {
  __shared__ f32x2 lds[4][DIMQ];     // 32 KB perm slices (per-wave private)
  const int lane = threadIdx.x & 63;
  const int w = threadIdx.x >> 6;
  const int row = blockIdx.x * 4 + w;
  f32x2* L = lds[w];
  const float4* gq  = (const float4*)Gg;
  const f32x2* D0   = (const f32x2*)(Gg + 256);
  const float4* Etab = (const float4*)(D0 + 1024);

  f32x2 s[16];

  // ---- load; init state = x * D_phi^0 (first diagonal on real input) ----
  const float* xr = X + (size_t)row * DIMQ;
  float ss = 0.f;
  #pragma unroll
  for (int e = 0; e < 16; ++e) {
    float v = xr[(e << 6) | lane];
    ss += v * v;
    s[e] = v * D0[(e << 6) | lane];
  }
  const float rn2 = 1.0f / red64(ss);   // uniform probability scale

  do_layer<0>(s, gq, Etab, L, lane);
  do_layer<1>(s, gq, Etab, L, lane);
  do_layer<2>(s, gq, Etab, L, lane);
  do_layer<3>(s, gq, Etab, L, lane);

  // ---- probs -> z via WHT (layer-3 perm r=4 folded into signs) ----
  float h[16];
  #pragma unroll
  for (int e = 0; e < 16; ++e) h[e] = s[e].x * s[e].x + s[e].y * s[e].y;
  wht<1>(h); wht<2>(h); wht<4>(h); wht<8>(h);

  float z[10];
  z[0] = zfin<0>(h, lane);
  z[1] = zfin<1>(h, lane);
  z[2] = zfin<2>(h, lane);
  z[3] = zfin<3>(h, lane);
  z[4] = zfin<4>(h, lane);
  z[5] = zfin<5>(h, lane);
  z[6] = zfin<6>(h, lane);
  z[7] = zfin<7>(h, lane);
  z[8] = zfin<8>(h, lane);
  z[9] = zfin<9>(h, lane);

  // ---- linear head (rn2 applied once) ----
  if (lane < 16) {
    float acc = 0.f;
    #pragma unroll
    for (int q = 0; q < 10; ++q) acc += z[q] * W[lane * 10 + q];
    out[(size_t)row * 16 + lane] = bias[lane] + rn2 * acc;
  }
}

extern "C" void kernel_launch(void* const* d_in, const int* in_sizes, int n_in,
                              void* d_out, int out_size, void* d_ws, size_t ws_size,
                              hipStream_t stream) {
  const float* X    = (const float*)d_in[0];
  const float* wts  = (const float*)d_in[1];
  const float* W    = (const float*)d_in[2];
  const float* bias = (const float*)d_in[3];
  float* out = (float*)d_out;
  float* Gg = (float*)d_ws;   // gq 160 + pad + D0 2048 + E 12288 floats ~= 59 KB

  hipLaunchKernelGGL(prep_g,  dim3(4),         dim3(256), 0, stream, wts, Gg);
  hipLaunchKernelGGL(vqc_sim, dim3(BATCH / 4), dim3(256), 0, stream, X, Gg, W, bias, out);
}